// Round 1
// baseline (140.922 us; speedup 1.0000x reference)
//
#include <hip/hip_runtime.h>
#include <math.h>

// Problem dims fixed by setup_inputs()
#define B 2
#define T 8
#define M 1024
#define NB 2048
#define N_RES 128
#define TILE 32
#define NTILES (M / TILE)                      // 32
#define NTPAIRS (NTILES * (NTILES + 1) / 2)    // 528

// workspace float offsets
#define WS_SCORE  0
#define WS_PAIRS  1
#define WS_STRUCT 2
#define WS_BONDN  3
#define WS_BONDD  4
#define WS_TCOUNT 5
#define WS_NVALID 6               // B entries (clamped to >=1)
#define WS_S0     8               // B entries
#define WS_FW     10              // B*T entries
#define WS_FLEXS  32              // B*N_RES
#define WS_FLEXC  (32 + B * N_RES)
#define WS_TOTAL  (32 + 2 * B * N_RES)   // 544 floats

__device__ inline float block_reduce(float v, float* smem) {
    int lane = threadIdx.x & 63, wid = threadIdx.x >> 6;
#pragma unroll
    for (int off = 32; off > 0; off >>= 1) v += __shfl_down(v, off, 64);
    __syncthreads();                 // protect smem reuse across calls
    if (lane == 0) smem[wid] = v;
    __syncthreads();
    float r = 0.f;
    if (threadIdx.x == 0) {
        int nw = (int)blockDim.x >> 6;
        for (int i = 0; i < nw; i++) r += smem[i];
    }
    return r;   // valid on thread 0 only
}

// ---- K0: tiny scalars: n_valid[b], target count, frame weights fw, S0 ----
__global__ void k_prep(const int* __restrict__ cond, const int* __restrict__ amask,
                       const int* __restrict__ omask, float* __restrict__ ws) {
    __shared__ float red[8];
    int tid = threadIdx.x;
    for (int b = 0; b < B; b++) {
        float local = 0.f;
        for (int m = tid; m < M; m += blockDim.x)
            local += (amask[b * M + m] && omask[b * M + m]) ? 1.f : 0.f;
        float tot = block_reduce(local, red);
        if (tid == 0) ws[WS_NVALID + b] = fmaxf(tot, 1.f);
    }
    if (tid == 0) {
        float tc = 0.f;
        for (int b = 0; b < B; b++) {
            float cb = 0.f;
            for (int t = 0; t < T; t++) cb += (cond[b * T + t] == 0) ? 1.f : 0.f;
            tc += cb;
            float denom = fmaxf(cb, 1.f);
            for (int t = 0; t < T; t++)
                ws[WS_FW + b * T + t] = ((cond[b * T + t] == 0) ? 1.f : 0.f) / denom;
            ws[WS_S0 + b] = cb / denom;   // == sum_t fw
        }
        ws[WS_TCOUNT] = fmaxf(tc, 1.f);
    }
}

// ---- structure loss: one block per (b,t) ----
__global__ void k_struct(const float* __restrict__ xp, const float* __restrict__ xg,
                         const float* __restrict__ sigma, const int* __restrict__ cond,
                         const int* __restrict__ amask, const int* __restrict__ omask,
                         const int* __restrict__ mtype, float* __restrict__ ws) {
    __shared__ float red[8];
    int b = blockIdx.x / T, t = blockIdx.x % T;
    const float molw[4] = {1.f, 5.f, 5.f, 10.f};
    const float* p = xp + (size_t)(b * T + t) * M * 3;
    const float* g = xg + (size_t)(b * T + t) * M * 3;
    float local = 0.f;
    for (int m = threadIdx.x; m < M; m += blockDim.x) {
        float w = (amask[b * M + m] && omask[b * M + m]) ? molw[mtype[b * M + m] & 3] : 0.f;
        float dx = p[m * 3 + 0] - g[m * 3 + 0];
        float dy = p[m * 3 + 1] - g[m * 3 + 1];
        float dz = p[m * 3 + 2] - g[m * 3 + 2];
        local += (dx * dx + dy * dy + dz * dz) * w;
    }
    float tot = block_reduce(local, red);
    if (threadIdx.x == 0) {
        float per_frame = tot / ws[WS_NVALID + b];
        float s = sigma[b * T + t];
        float targ = (cond[b * T + t] == 0) ? 1.f : 0.f;
        float denom = s * 16.0f + 1e-8f;
        float edm = (s * s + 256.0f) / (denom * denom) * targ;
        atomicAdd(ws + WS_STRUCT, edm * per_frame);
    }
}

// ---- bond loss: one thread per (b,t,k) ----
__global__ void k_bond(const float* __restrict__ xp, const float* __restrict__ blen,
                       const int* __restrict__ cond, const int* __restrict__ bidx,
                       const int* __restrict__ bmask, float* __restrict__ ws) {
    __shared__ float red[8], red2[8];
    int gid = blockIdx.x * blockDim.x + threadIdx.x;
    float num = 0.f, den = 0.f;
    if (gid < B * T * NB) {
        int b = gid / (T * NB);
        int r = gid % (T * NB);
        int t = r / NB, k = r % NB;
        float w = ((cond[b * T + t] == 0) && bmask[b * NB + k]) ? 1.f : 0.f;
        int i = bidx[(b * NB + k) * 2 + 0];
        int j = bidx[(b * NB + k) * 2 + 1];
        const float* base = xp + (size_t)(b * T + t) * M * 3;
        float dx = base[i * 3 + 0] - base[j * 3 + 0];
        float dy = base[i * 3 + 1] - base[j * 3 + 1];
        float dz = base[i * 3 + 2] - base[j * 3 + 2];
        float len = sqrtf(dx * dx + dy * dy + dz * dz + 1e-12f);
        float d = len - blen[b * NB + k];
        num = w * d * d;
        den = w;
    }
    float n = block_reduce(num, red);
    float d2 = block_reduce(den, red2);
    if (threadIdx.x == 0) {
        atomicAdd(ws + WS_BONDN, n);
        atomicAdd(ws + WS_BONDD, d2);
    }
}

// ---- fused pairwise: lDDT + flexibility. One block per (b, tile_i<=tile_j). ----
__global__ __launch_bounds__(256) void k_pair(const float* __restrict__ xp,
                                              const float* __restrict__ xg,
                                              const int* __restrict__ cond,
                                              const int* __restrict__ amask,
                                              const int* __restrict__ omask,
                                              const int* __restrict__ resid,
                                              float* __restrict__ ws) {
    __shared__ float spi[T][TILE][3], sgi[T][TILE][3], spj[T][TILE][3], sgj[T][TILE][3];
    __shared__ float s_fw[T];
    __shared__ int s_targ[T];
    __shared__ int s_res[2][TILE];
    __shared__ float s_val[2][TILE];
    __shared__ float red[8], red2[8];

    int tid = threadIdx.x;
    int b = blockIdx.x / NTPAIRS;
    int p = blockIdx.x % NTPAIRS;
    int ti = 0, rem = p;
    while (rem >= NTILES - ti) { rem -= NTILES - ti; ti++; }
    int tj = ti + rem;

    if (tid < T) {
        s_fw[tid] = ws[WS_FW + b * T + tid];
        s_targ[tid] = (cond[b * T + tid] == 0) ? 1 : 0;
    }
    if (tid < TILE) {
        int i = ti * TILE + tid;
        s_res[0][tid] = resid[b * M + i];
        s_val[0][tid] = (amask[b * M + i] && omask[b * M + i]) ? 1.f : 0.f;
        int j = tj * TILE + tid;
        s_res[1][tid] = resid[b * M + j];
        s_val[1][tid] = (amask[b * M + j] && omask[b * M + j]) ? 1.f : 0.f;
    }
    const size_t basep = (size_t)b * T * M * 3;
    for (int e = tid; e < T * TILE * 3; e += 256) {
        int t = e / (TILE * 3);
        int r = e - t * (TILE * 3);
        size_t gi = basep + (size_t)t * M * 3 + (size_t)ti * TILE * 3 + r;
        size_t gj = basep + (size_t)t * M * 3 + (size_t)tj * TILE * 3 + r;
        (&spi[0][0][0])[e] = xp[gi];
        (&sgi[0][0][0])[e] = xg[gi];
        (&spj[0][0][0])[e] = xp[gj];
        (&sgj[0][0][0])[e] = xg[gj];
    }
    __syncthreads();

    float S0b = ws[WS_S0 + b];
    float score_sum = 0.f, cnt_sum = 0.f;

#pragma unroll
    for (int k = 0; k < (TILE * TILE) / 256; k++) {
        int q = tid + k * 256;
        int ii = q >> 5, jj = q & (TILE - 1);
        int i = ti * TILE + ii, j = tj * TILE + jj;
        if (i >= j) continue;                       // strict upper triangle
        float vij = s_val[0][ii] * s_val[1][jj];
        float S1p = 0.f, S2p = 0.f, S1g = 0.f, S2g = 0.f;
#pragma unroll
        for (int t = 0; t < T; t++) {
            float dx = spi[t][ii][0] - spj[t][jj][0];
            float dy = spi[t][ii][1] - spj[t][jj][1];
            float dz = spi[t][ii][2] - spj[t][jj][2];
            float dp = sqrtf(fmaxf(dx * dx + dy * dy + dz * dz, 1e-12f));
            dx = sgi[t][ii][0] - sgj[t][jj][0];
            dy = sgi[t][ii][1] - sgj[t][jj][1];
            dz = sgi[t][ii][2] - sgj[t][jj][2];
            float dg = sqrtf(fmaxf(dx * dx + dy * dy + dz * dz, 1e-12f));
            float fw = s_fw[t];
            S1p += fw * dp; S2p += fw * dp * dp;
            S1g += fw * dg; S2g += fw * dg * dg;
            if (s_targ[t] && vij > 0.f && dg < 15.0f) {
                float diff = fabsf(dp - dg);
                float ed = __expf(-diff);
                // sum_k sigmoid(th_k - diff), th = {0.5,1,2,4}; e^th precomputed
                float e0 = 1.64872127070013f * ed;
                float e1 = 2.71828182845905f * ed;
                float e2 = 7.38905609893065f * ed;
                float e3 = 54.5981500331442f * ed;
                score_sum += 0.25f * (e0 / (1.f + e0) + e1 / (1.f + e1) +
                                      e2 / (1.f + e2) + e3 / (1.f + e3));
                cnt_sum += 1.f;
            }
        }
        // flexibility: same-residue upper-triangle valid pairs
        if (vij > 0.f && s_res[0][ii] == s_res[1][jj]) {
            // sum_t fw (d-m)^2 = S2 - S1^2 (2 - S0), m = S1
            float varp = fmaxf(S2p - S1p * S1p * (2.f - S0b), 0.f);
            float varg = fmaxf(S2g - S1g * S1g * (2.f - S0b), 0.f);
            float dstd = sqrtf(varp + 1e-8f) - sqrtf(varg + 1e-8f);
            int seg = b * N_RES + s_res[0][ii];
            atomicAdd(ws + WS_FLEXS + seg, dstd * dstd);
            atomicAdd(ws + WS_FLEXC + seg, 1.f);
        }
    }
    float sc = block_reduce(score_sum, red);
    float ct = block_reduce(cnt_sum, red2);
    if (tid == 0) {
        atomicAdd(ws + WS_SCORE, 2.f * sc);   // i<j computed once, dmask is symmetric
        atomicAdd(ws + WS_PAIRS, 2.f * ct);
    }
}

// ---- final combine ----
__global__ void k_final(const float* __restrict__ ws, float* __restrict__ out) {
    __shared__ float red[8], red2[8];
    int tid = threadIdx.x;
    float s_local = 0.f, n_local = 0.f;
    for (int seg = tid; seg < B * N_RES; seg += 256) {
        float c = ws[WS_FLEXC + seg];
        if (c > 0.f) { s_local += ws[WS_FLEXS + seg] / c; n_local += 1.f; }
    }
    float ssum = block_reduce(s_local, red);
    float nsum = block_reduce(n_local, red2);
    if (tid == 0) {
        float l_local = ssum / fmaxf(nsum, 1.f);
        float l_struct = ws[WS_STRUCT] / ws[WS_TCOUNT];
        float l_bond = ws[WS_BONDN] / fmaxf(ws[WS_BONDD], 1.f);
        float l_lddt = 1.f - ws[WS_SCORE] / fmaxf(ws[WS_PAIRS], 1.f);
        // total = l_struct + ALPHA_BOND*l_bond + l_lddt + BETA_FLEX*BETA_REL_L*l_local
        out[0] = l_struct + l_bond + l_lddt + 4.0f * l_local;
    }
}

extern "C" void kernel_launch(void* const* d_in, const int* in_sizes, int n_in,
                              void* d_out, int out_size, void* d_ws, size_t ws_size,
                              hipStream_t stream) {
    const float* xp    = (const float*)d_in[0];   // (B,T,M,3)
    const float* xg    = (const float*)d_in[1];   // (B,T,M,3)
    const float* sigma = (const float*)d_in[2];   // (B,T)
    const float* blen  = (const float*)d_in[3];   // (B,NB)
    const int*   cond  = (const int*)d_in[4];     // (B,T) bool->int32
    const int*   amask = (const int*)d_in[5];     // (B,M)
    const int*   omask = (const int*)d_in[6];     // (B,M)
    const int*   mtype = (const int*)d_in[7];     // (B,M)
    const int*   resid = (const int*)d_in[8];     // (B,M)
    const int*   bidx  = (const int*)d_in[9];     // (B,NB,2)
    const int*   bmask = (const int*)d_in[10];    // (B,NB)
    float* out = (float*)d_out;
    float* ws  = (float*)d_ws;

    hipMemsetAsync(ws, 0, WS_TOTAL * sizeof(float), stream);
    k_prep<<<1, 256, 0, stream>>>(cond, amask, omask, ws);
    k_struct<<<B * T, 256, 0, stream>>>(xp, xg, sigma, cond, amask, omask, mtype, ws);
    k_bond<<<(B * T * NB + 255) / 256, 256, 0, stream>>>(xp, blen, cond, bidx, bmask, ws);
    k_pair<<<B * NTPAIRS, 256, 0, stream>>>(xp, xg, cond, amask, omask, resid, ws);
    k_final<<<1, 256, 0, stream>>>(ws, out);
}